// Round 11
// baseline (173.325 us; speedup 1.0000x reference)
//
#include <hip/hip_runtime.h>

typedef unsigned short u16;
typedef unsigned char u8;
typedef unsigned int u32;
typedef __bf16 bf16x8 __attribute__((ext_vector_type(8)));
typedef float  f32x16 __attribute__((ext_vector_type(16)));
typedef int    i32x4  __attribute__((ext_vector_type(4)));
typedef int    i32x16 __attribute__((ext_vector_type(16)));

#define NB 4
#define NN 4096
#define ND 256

#define QPV (127.0f / 4.5f)        // pv quant scale
#define DPV (4.5f / 16129.0f)      // O dequant
#define QST (127.0f / 4.6f)        // state quant scale
#define DST (4.6f / 16129.0f)      // ds dequant
#define MAGIC 12582912.0f          // 1.5*2^23: fma(x,s,MAGIC) -> low byte = int8(x*s) rne

__device__ __forceinline__ u16 f2bf(float x) { return __builtin_bit_cast(u16, (__bf16)x); }
__device__ __forceinline__ u32 fbits(float x) { return __builtin_bit_cast(u32, x); }

// pack low bytes of 4 magic-biased floats into one dword (3 x v_perm_b32)
__device__ __forceinline__ u32 packlow4(float a, float b, float c, float d) {
    u32 p = __builtin_amdgcn_perm(fbits(b), fbits(a), 0x00000400u);
    u32 q = __builtin_amdgcn_perm(fbits(d), fbits(c), 0x00000400u);
    return __builtin_amdgcn_perm(q, p, 0x05040100u);
}

// ---- sigma k-order convention (R9): position (h, byte 4g+j) holds logical
// m = 8g+j+4h on BOTH the pf (A) and vp8 (B) sides -> MFMA k-sum bit-identical,
// no cross-half shuffle, no LDS transpose in prep.

// ws layout:
//  kq8 : [b*128+strip][s8][lane64][16B]    i8 val frags, 4 MB
//  vp8 : [b*128+strip][slot9][lane64][16B] i8 frags (sigma): slot0..7 pv^T, slot8 state, 4.5 MB
//  wv  : [es8][s16][lane64][8]             bf16 Wv^T frags, 128 KB
//  srow: [b*4096+n] f32 = rowmax/127, 64 KB

// ---- Wv frag prep (runs first, 8 blocks) ----
__global__ __launch_bounds__(256) void k_wv(const float* __restrict__ Wv, u16* __restrict__ wv) {
    __shared__ u16 t2[256 * 33];
    int tid = threadIdx.x;
    int es = blockIdx.x, e0 = es * 32;
    #pragma unroll
    for (int k = 0; k < 8; k++) {
        int idx = tid + k * 256;
        int row = idx >> 3, c4 = idx & 7;
        float4 v = *(const float4*)(Wv + row * 256 + e0 + c4 * 4);
        u16* p = t2 + row * 33 + c4 * 4;
        p[0] = f2bf(v.x); p[1] = f2bf(v.y); p[2] = f2bf(v.z); p[3] = f2bf(v.w);
    }
    __syncthreads();
    u16* dst = wv + (size_t)es * 16 * 512;
    #pragma unroll
    for (int k = 0; k < 4; k++) {
        int flat = tid + k * 256;
        int s = flat >> 6, l = flat & 63;
        int l31 = l & 31, h = l >> 5;
        union { u16 o[8]; uint4 q; } u;
        #pragma unroll
        for (int j = 0; j < 8; j++) u.o[j] = t2[(s * 16 + h * 8 + j) * 33 + l31];
        *(uint4*)(dst + (size_t)flat * 8) = u.q;
    }
}

// ---- prep: stage strip, rowmax, kq8 frags, FUSED pv -> vp8 frags (sigma-order) ----
__global__ __launch_bounds__(256) void k_prep(const float* __restrict__ val,
                                              const float* __restrict__ state,
                                              const u16* __restrict__ wvf,
                                              u8* __restrict__ kq8,
                                              float* __restrict__ srow,
                                              u8* __restrict__ vp8) {
    int tid = threadIdx.x;
    int bid = blockIdx.x;
    if (bid < 512) {
        __shared__ float t[32 * 257];
        __shared__ float rmax[32];
        const float* src = val + (size_t)bid * 32 * 256;
        #pragma unroll
        for (int k = 0; k < 8; k++) {
            int idx = tid + k * 256;
            int row = idx >> 6, c4 = idx & 63;
            float4 v = *(const float4*)(src + row * 256 + c4 * 4);
            float* p = t + row * 257 + c4 * 4;
            p[0] = v.x; p[1] = v.y; p[2] = v.z; p[3] = v.w;
        }
        __syncthreads();
        {
            int row = tid >> 3, seg = tid & 7;
            float m = 0.0f;
            #pragma unroll
            for (int i = 0; i < 32; i++) m = fmaxf(m, fabsf(t[row * 257 + seg + i * 8]));
            m = fmaxf(m, __shfl_down(m, 4));
            m = fmaxf(m, __shfl_down(m, 2));
            m = fmaxf(m, __shfl_down(m, 1));
            if (seg == 0) {
                m = fmaxf(m, 1e-20f);
                rmax[row] = m;
                srow[bid * 32 + row] = m * (1.0f / 127.0f);
            }
        }
        __syncthreads();
        // i8 frags, per-row scale; |val|<=rmax so no clamp needed
        u8* dst8 = kq8 + (size_t)bid * 8192;
        #pragma unroll
        for (int k = 0; k < 2; k++) {
            int flat = tid + k * 256;
            int s = flat >> 6, l = flat & 63;
            int l31 = l & 31, h = l >> 5;
            float r127 = 127.0f / rmax[l31];
            const float* p = t + l31 * 257 + s * 32 + h * 16;
            u32 d[4];
            #pragma unroll
            for (int g = 0; g < 4; g++)
                d[g] = packlow4(fmaf(p[4 * g + 0], r127, MAGIC), fmaf(p[4 * g + 1], r127, MAGIC),
                                fmaf(p[4 * g + 2], r127, MAGIC), fmaf(p[4 * g + 3], r127, MAGIC));
            *(uint4*)(dst8 + (size_t)flat * 16) = make_uint4(d[0], d[1], d[2], d[3]);
        }
        // fused pv, sigma-order write (no LDS transpose)
        {
            int w = tid >> 6, lane = tid & 63;
            int l31 = lane & 31, h = lane >> 5;
            const u16* wv0 = wvf + ((size_t)((w * 2 + 0) * 16)) * 512 + lane * 8;
            const u16* wv1 = wvf + ((size_t)((w * 2 + 1) * 16)) * 512 + lane * 8;
            f32x16 acc0 = {}, acc1 = {};
            for (int s = 0; s < 16; s++) {
                union { u16 o[8]; bf16x8 v; } ua;
                const float* p = t + l31 * 257 + s * 16 + h * 8;
                #pragma unroll
                for (int j = 0; j < 8; j++) ua.o[j] = f2bf(p[j]);
                bf16x8 b0 = *(const bf16x8*)(wv0 + (size_t)s * 512);
                bf16x8 b1 = *(const bf16x8*)(wv1 + (size_t)s * 512);
                acc0 = __builtin_amdgcn_mfma_f32_32x32x16_bf16(ua.v, b0, acc0, 0, 0, 0);
                acc1 = __builtin_amdgcn_mfma_f32_32x32x16_bf16(ua.v, b1, acc1, 0, 0, 0);
            }
            union { u32 wd[4]; i32x4 v; } o0, o1;
            #pragma unroll
            for (int g = 0; g < 4; g++) {
                o0.wd[g] = packlow4(
                    fminf(fmaxf(acc0[4 * g + 0] * QPV, -127.0f), 127.0f) + MAGIC,
                    fminf(fmaxf(acc0[4 * g + 1] * QPV, -127.0f), 127.0f) + MAGIC,
                    fminf(fmaxf(acc0[4 * g + 2] * QPV, -127.0f), 127.0f) + MAGIC,
                    fminf(fmaxf(acc0[4 * g + 3] * QPV, -127.0f), 127.0f) + MAGIC);
                o1.wd[g] = packlow4(
                    fminf(fmaxf(acc1[4 * g + 0] * QPV, -127.0f), 127.0f) + MAGIC,
                    fminf(fmaxf(acc1[4 * g + 1] * QPV, -127.0f), 127.0f) + MAGIC,
                    fminf(fmaxf(acc1[4 * g + 2] * QPV, -127.0f), 127.0f) + MAGIC,
                    fminf(fmaxf(acc1[4 * g + 3] * QPV, -127.0f), 127.0f) + MAGIC);
            }
            *(i32x4*)(vp8 + ((size_t)(bid * 9 + w * 2 + 0)) * 1024 + lane * 16) = o0.v;
            *(i32x4*)(vp8 + ((size_t)(bid * 9 + w * 2 + 1)) * 1024 + lane * 16) = o1.v;
        }
    } else {
        int b = bid - 512;
        __shared__ u8 qs[4096];
        #pragma unroll
        for (int k = 0; k < 16; k++) {
            int i = tid + k * 256;
            float x = fminf(fmaxf(state[b * 4096 + i] * QST, -127.0f), 127.0f);
            qs[i] = (u8)(fbits(x + MAGIC) & 255);
        }
        __syncthreads();
        // slot 8 in sigma-order: dword g of lane (l31,h) = qs[strip*32 + 8g + 4h]
        #pragma unroll
        for (int k = 0; k < 32; k++) {
            int chunk = tid + k * 256;
            int strip = chunk >> 6, lane = chunk & 63, h = (lane >> 5) & 1;
            union { u32 wd[4]; i32x4 v; } u;
            #pragma unroll
            for (int g = 0; g < 4; g++)
                u.wd[g] = *(const u32*)(qs + strip * 32 + 8 * g + 4 * h);
            *(i32x4*)(vp8 + ((size_t)((b * 128 + strip) * 9 + 8)) * 1024 + (chunk & 63) * 16) = u.v;
        }
    }
}

// ---- main (R11): register-diet loop targeting 3 waves/SIMD (total regs <= 170).
// Single QK acc chain (int add associative -> bit-identical); all loads for iter
// mt issued within iter mt (kf/sg/sf at top, vf after dequant, dying in PV);
// no cross-iter prefetch. launch_bounds(256,3) caps unified VGPR+AGPR at 170.
__global__ __launch_bounds__(256, 3) void k_main(const u8* __restrict__ kq8,
                                                 const u8* __restrict__ vp8,
                                                 const float* __restrict__ srow,
                                                 float* __restrict__ ds_out,
                                                 float* __restrict__ dval_out) {
    __shared__ i32x4 pbuf[2][4][64];           // P frag exchange, double-buffered (8 KB)
    __shared__ int dsqi[4][32];

    int tid = threadIdx.x;
    int w = tid >> 6, lane = tid & 63;
    int l31 = lane & 31, h = lane >> 5;

    int id = blockIdx.x;                       // [0,512)
    int xcd = id & 7;
    int bb = xcd >> 1;
    int t7 = ((xcd & 1) << 6) | (id >> 3);     // q-strip [0,128)
    int q0 = t7 * 32;
    size_t bbase = (size_t)bb * 128;

    i32x4 qf[8];
    {
        const u8* qsrc = kq8 + (bbase + t7) * 8192 + lane * 16;
        #pragma unroll
        for (int s = 0; s < 8; s++) qf[s] = *(const i32x4*)(qsrc + (size_t)s * 1024);
    }
    float srq = srow[bb * 4096 + q0 + l31];

    i32x16 oacc[2] = {};
    i32x16 dsa = {};

    for (int mt = 0; mt < 32; mt++) {
        // iter-local loads: kf (8x16B), scales, state frag — issued together, then QK
        const u8* kb = kq8 + (bbase + mt * 4 + w) * 8192 + lane * 16;
        i32x4 kf[8];
        #pragma unroll
        for (int s = 0; s < 8; s++) kf[s] = *(const i32x4*)(kb + (size_t)s * 1024);
        const float* srm = srow + bb * 4096 + mt * 128 + w * 32;
        float4 sg[4];
        #pragma unroll
        for (int g = 0; g < 4; g++) sg[g] = *(const float4*)(srm + g * 8 + h * 4);
        i32x4 sf = *(const i32x4*)(vp8 + ((size_t)((bbase + mt * 4 + w) * 9 + 8)) * 1024 + lane * 16);

        // S^T = K x Q^T, single accumulator chain (-16 acc regs vs dual chain)
        i32x16 sacc = {};
        #pragma unroll
        for (int s = 0; s < 8; s++)
            sacc = __builtin_amdgcn_mfma_i32_32x32x32_i8(kf[s], qf[s], sacc, 0, 0, 0);

        // dequant -> softsign -> magic-round to i8 (rne), pack in sigma order
        float cf[16];
        #pragma unroll
        for (int r = 0; r < 16; r++) {
            float sm = ((const float*)&sg[r >> 2])[r & 3] * srq;
            float xs = (float)sacc[r] * sm;
            float p = xs * __builtin_amdgcn_rcpf(1.0f + fabsf(xs));
            cf[r] = fmaf(p, 127.0f, MAGIC);
        }
        union { u32 wd[4]; i32x4 v; } pu;
        pu.wd[0] = packlow4(cf[0], cf[1], cf[2], cf[3]);
        pu.wd[1] = packlow4(cf[4], cf[5], cf[6], cf[7]);
        pu.wd[2] = packlow4(cf[8], cf[9], cf[10], cf[11]);
        pu.wd[3] = packlow4(cf[12], cf[13], cf[14], cf[15]);
        i32x4 pf = pu.v;

        // ds partial for this wave's strip
        dsa = __builtin_amdgcn_mfma_i32_32x32x32_i8(pf, sf, dsa, 0, 0, 0);

        // issue this iter's vf loads BEFORE the barrier (latency hides under
        // pack + barrier wait); they die inside PV below
        i32x4 vf[4][2];
        #pragma unroll
        for (int st = 0; st < 4; st++)
            #pragma unroll
            for (int e = 0; e < 2; e++)
                vf[st][e] = *(const i32x4*)(vp8 + ((size_t)((bbase + mt * 4 + st) * 9 + 2 * w + e)) * 1024 + lane * 16);

        // share P frags across waves (write(i) -> barrier(i) -> read(i); dbuf safe)
        pbuf[mt & 1][w][lane] = pf;
        __syncthreads();
        i32x4 pl[4];
        #pragma unroll
        for (int st = 0; st < 4; st++) pl[st] = pbuf[mt & 1][st][lane];

        // O(cols 2w,2w+1) += sum_st P(st) x Vt(st)
        #pragma unroll
        for (int st = 0; st < 4; st++) {
            oacc[0] = __builtin_amdgcn_mfma_i32_32x32x32_i8(pl[st], vf[st][0], oacc[0], 0, 0, 0);
            oacc[1] = __builtin_amdgcn_mfma_i32_32x32x32_i8(pl[st], vf[st][1], oacc[1], 0, 0, 0);
        }
    }

    // ---- epilogue: no cross-wave O reduction needed; each wave owns its cols ----
    if (l31 == 0) {
        #pragma unroll
        for (int r = 0; r < 16; r++) dsqi[w][(r & 3) + 8 * (r >> 2) + 4 * h] = dsa[r];
    }
    #pragma unroll
    for (int e = 0; e < 2; e++) {
        #pragma unroll
        for (int r = 0; r < 16; r++) {
            int row = (r & 3) + 8 * (r >> 2) + 4 * h;
            dval_out[((size_t)(bb * 4096 + q0 + row)) * 256 + (2 * w + e) * 32 + l31] =
                (float)oacc[e][r] * DPV;
        }
    }
    __syncthreads();
    if (w == 0 && lane < 32) {
        int d = dsqi[0][lane] + dsqi[1][lane] + dsqi[2][lane] + dsqi[3][lane];
        ds_out[bb * 4096 + q0 + lane] = (float)d * DST;
    }
}

extern "C" void kernel_launch(void* const* d_in, const int* in_sizes, int n_in,
                              void* d_out, int out_size, void* d_ws, size_t ws_size,
                              hipStream_t stream) {
    const float* val   = (const float*)d_in[0];
    const float* state = (const float*)d_in[1];
    const float* Wv    = (const float*)d_in[2];

    float* ds_out   = (float*)d_out;
    float* dval_out = ds_out + NB * NN;

    u8*  kq8 = (u8*)d_ws;                                      // 4 MB
    u8*  vp8 = kq8 + (size_t)NB * NN * ND;                     // 4.5 MB
    u16* wv  = (u16*)(vp8 + (size_t)NB * 128 * 9216);          // 128 KB
    float* srow = (float*)(wv + 8 * 16 * 512);                 // 64 KB

    k_wv<<<8, 256, 0, stream>>>(Wv, wv);
    k_prep<<<516, 256, 0, stream>>>(val, state, wv, kq8, srow, vp8);
    k_main<<<512, 256, 0, stream>>>(kq8, vp8, srow, ds_out, dval_out);
}

// Round 12
// 136.395 us; speedup vs baseline: 1.2708x; 1.2708x over previous
//
#include <hip/hip_runtime.h>

typedef unsigned short u16;
typedef unsigned char u8;
typedef unsigned int u32;
typedef __bf16 bf16x8 __attribute__((ext_vector_type(8)));
typedef float  f32x16 __attribute__((ext_vector_type(16)));
typedef int    i32x4  __attribute__((ext_vector_type(4)));
typedef int    i32x16 __attribute__((ext_vector_type(16)));

#define NB 4
#define NN 4096
#define ND 256

#define QPV (127.0f / 4.5f)        // pv quant scale
#define DPV (4.5f / 16129.0f)      // O dequant
#define QST (127.0f / 4.6f)        // state quant scale
#define DST (4.6f / 16129.0f)      // ds dequant
#define MAGIC 12582912.0f          // 1.5*2^23: fma(x,s,MAGIC) -> low byte = int8(x*s) rne

__device__ __forceinline__ u16 f2bf(float x) { return __builtin_bit_cast(u16, (__bf16)x); }
__device__ __forceinline__ u32 fbits(float x) { return __builtin_bit_cast(u32, x); }

// pack low bytes of 4 magic-biased floats into one dword (3 x v_perm_b32)
__device__ __forceinline__ u32 packlow4(float a, float b, float c, float d) {
    u32 p = __builtin_amdgcn_perm(fbits(b), fbits(a), 0x00000400u);
    u32 q = __builtin_amdgcn_perm(fbits(d), fbits(c), 0x00000400u);
    return __builtin_amdgcn_perm(q, p, 0x05040100u);
}

// ---- sigma k-order convention (R9): position (h, byte 4g+j) holds logical
// m = 8g+j+4h on BOTH the pf (A) and vp8 (B) sides -> MFMA k-sum bit-identical,
// no cross-half shuffle, no LDS transpose in prep.

// ws layout:
//  kq8 : [b*128+strip][s8][lane64][16B]    i8 val frags, 4 MB
//  vp8 : [b*128+strip][slot9][lane64][16B] i8 frags (sigma): slot0..7 pv^T, slot8 state, 4.5 MB
//  wv  : [es8][s16][lane64][8]             bf16 Wv^T frags, 128 KB
//  srow: [b*4096+n] f32 = rowmax/127, 64 KB

// ---- Wv frag prep (runs first, 8 blocks) ----
__global__ __launch_bounds__(256) void k_wv(const float* __restrict__ Wv, u16* __restrict__ wv) {
    __shared__ u16 t2[256 * 33];
    int tid = threadIdx.x;
    int es = blockIdx.x, e0 = es * 32;
    #pragma unroll
    for (int k = 0; k < 8; k++) {
        int idx = tid + k * 256;
        int row = idx >> 3, c4 = idx & 7;
        float4 v = *(const float4*)(Wv + row * 256 + e0 + c4 * 4);
        u16* p = t2 + row * 33 + c4 * 4;
        p[0] = f2bf(v.x); p[1] = f2bf(v.y); p[2] = f2bf(v.z); p[3] = f2bf(v.w);
    }
    __syncthreads();
    u16* dst = wv + (size_t)es * 16 * 512;
    #pragma unroll
    for (int k = 0; k < 4; k++) {
        int flat = tid + k * 256;
        int s = flat >> 6, l = flat & 63;
        int l31 = l & 31, h = l >> 5;
        union { u16 o[8]; uint4 q; } u;
        #pragma unroll
        for (int j = 0; j < 8; j++) u.o[j] = t2[(s * 16 + h * 8 + j) * 33 + l31];
        *(uint4*)(dst + (size_t)flat * 8) = u.q;
    }
}

// ---- prep: stage strip, rowmax, kq8 frags, FUSED pv -> vp8 frags (sigma-order) ----
__global__ __launch_bounds__(256) void k_prep(const float* __restrict__ val,
                                              const float* __restrict__ state,
                                              const u16* __restrict__ wvf,
                                              u8* __restrict__ kq8,
                                              float* __restrict__ srow,
                                              u8* __restrict__ vp8) {
    int tid = threadIdx.x;
    int bid = blockIdx.x;
    if (bid < 512) {
        __shared__ float t[32 * 257];
        __shared__ float rmax[32];
        const float* src = val + (size_t)bid * 32 * 256;
        #pragma unroll
        for (int k = 0; k < 8; k++) {
            int idx = tid + k * 256;
            int row = idx >> 6, c4 = idx & 63;
            float4 v = *(const float4*)(src + row * 256 + c4 * 4);
            float* p = t + row * 257 + c4 * 4;
            p[0] = v.x; p[1] = v.y; p[2] = v.z; p[3] = v.w;
        }
        __syncthreads();
        {
            int row = tid >> 3, seg = tid & 7;
            float m = 0.0f;
            #pragma unroll
            for (int i = 0; i < 32; i++) m = fmaxf(m, fabsf(t[row * 257 + seg + i * 8]));
            m = fmaxf(m, __shfl_down(m, 4));
            m = fmaxf(m, __shfl_down(m, 2));
            m = fmaxf(m, __shfl_down(m, 1));
            if (seg == 0) {
                m = fmaxf(m, 1e-20f);
                rmax[row] = m;
                srow[bid * 32 + row] = m * (1.0f / 127.0f);
            }
        }
        __syncthreads();
        // i8 frags, per-row scale; |val|<=rmax so no clamp needed
        u8* dst8 = kq8 + (size_t)bid * 8192;
        #pragma unroll
        for (int k = 0; k < 2; k++) {
            int flat = tid + k * 256;
            int s = flat >> 6, l = flat & 63;
            int l31 = l & 31, h = l >> 5;
            float r127 = 127.0f / rmax[l31];
            const float* p = t + l31 * 257 + s * 32 + h * 16;
            u32 d[4];
            #pragma unroll
            for (int g = 0; g < 4; g++)
                d[g] = packlow4(fmaf(p[4 * g + 0], r127, MAGIC), fmaf(p[4 * g + 1], r127, MAGIC),
                                fmaf(p[4 * g + 2], r127, MAGIC), fmaf(p[4 * g + 3], r127, MAGIC));
            *(uint4*)(dst8 + (size_t)flat * 16) = make_uint4(d[0], d[1], d[2], d[3]);
        }
        // fused pv, sigma-order write (no LDS transpose)
        {
            int w = tid >> 6, lane = tid & 63;
            int l31 = lane & 31, h = lane >> 5;
            const u16* wv0 = wvf + ((size_t)((w * 2 + 0) * 16)) * 512 + lane * 8;
            const u16* wv1 = wvf + ((size_t)((w * 2 + 1) * 16)) * 512 + lane * 8;
            f32x16 acc0 = {}, acc1 = {};
            for (int s = 0; s < 16; s++) {
                union { u16 o[8]; bf16x8 v; } ua;
                const float* p = t + l31 * 257 + s * 16 + h * 8;
                #pragma unroll
                for (int j = 0; j < 8; j++) ua.o[j] = f2bf(p[j]);
                bf16x8 b0 = *(const bf16x8*)(wv0 + (size_t)s * 512);
                bf16x8 b1 = *(const bf16x8*)(wv1 + (size_t)s * 512);
                acc0 = __builtin_amdgcn_mfma_f32_32x32x16_bf16(ua.v, b0, acc0, 0, 0, 0);
                acc1 = __builtin_amdgcn_mfma_f32_32x32x16_bf16(ua.v, b1, acc1, 0, 0, 0);
            }
            union { u32 wd[4]; i32x4 v; } o0, o1;
            #pragma unroll
            for (int g = 0; g < 4; g++) {
                o0.wd[g] = packlow4(
                    fminf(fmaxf(acc0[4 * g + 0] * QPV, -127.0f), 127.0f) + MAGIC,
                    fminf(fmaxf(acc0[4 * g + 1] * QPV, -127.0f), 127.0f) + MAGIC,
                    fminf(fmaxf(acc0[4 * g + 2] * QPV, -127.0f), 127.0f) + MAGIC,
                    fminf(fmaxf(acc0[4 * g + 3] * QPV, -127.0f), 127.0f) + MAGIC);
                o1.wd[g] = packlow4(
                    fminf(fmaxf(acc1[4 * g + 0] * QPV, -127.0f), 127.0f) + MAGIC,
                    fminf(fmaxf(acc1[4 * g + 1] * QPV, -127.0f), 127.0f) + MAGIC,
                    fminf(fmaxf(acc1[4 * g + 2] * QPV, -127.0f), 127.0f) + MAGIC,
                    fminf(fmaxf(acc1[4 * g + 3] * QPV, -127.0f), 127.0f) + MAGIC);
            }
            *(i32x4*)(vp8 + ((size_t)(bid * 9 + w * 2 + 0)) * 1024 + lane * 16) = o0.v;
            *(i32x4*)(vp8 + ((size_t)(bid * 9 + w * 2 + 1)) * 1024 + lane * 16) = o1.v;
        }
    } else {
        int b = bid - 512;
        __shared__ u8 qs[4096];
        #pragma unroll
        for (int k = 0; k < 16; k++) {
            int i = tid + k * 256;
            float x = fminf(fmaxf(state[b * 4096 + i] * QST, -127.0f), 127.0f);
            qs[i] = (u8)(fbits(x + MAGIC) & 255);
        }
        __syncthreads();
        // slot 8 in sigma-order: dword g of lane (l31,h) = qs[strip*32 + 8g + 4h]
        #pragma unroll
        for (int k = 0; k < 32; k++) {
            int chunk = tid + k * 256;
            int strip = chunk >> 6, lane = chunk & 63, h = (lane >> 5) & 1;
            union { u32 wd[4]; i32x4 v; } u;
            #pragma unroll
            for (int g = 0; g < 4; g++)
                u.wd[g] = *(const u32*)(qs + strip * 32 + 8 * g + 4 * h);
            *(i32x4*)(vp8 + ((size_t)((b * 128 + strip) * 9 + 8)) * 1024 + (chunk & 63) * 16) = u.v;
        }
    }
}

// ---- main (R12 = R9 + T5 setprio around MFMA clusters): et-split waves +
// LDS P-exchange, 1 barrier/iter; sigma-order pf (no shuffles); kf/vf/sf/sg
// single-buffer register prefetch. setprio(1) favors MFMA-phase waves over the
// phase-staggered co-resident block's load/VALU-phase waves (attn-like case).
__global__ __launch_bounds__(256, 2) void k_main(const u8* __restrict__ kq8,
                                                 const u8* __restrict__ vp8,
                                                 const float* __restrict__ srow,
                                                 float* __restrict__ ds_out,
                                                 float* __restrict__ dval_out) {
    __shared__ i32x4 pbuf[2][4][64];           // P frag exchange, double-buffered (8 KB)
    __shared__ int dsqi[4][32];

    int tid = threadIdx.x;
    int w = tid >> 6, lane = tid & 63;
    int l31 = lane & 31, h = lane >> 5;

    int id = blockIdx.x;                       // [0,512)
    int xcd = id & 7;
    int bb = xcd >> 1;
    int t7 = ((xcd & 1) << 6) | (id >> 3);     // q-strip [0,128)
    int q0 = t7 * 32;
    size_t bbase = (size_t)bb * 128;

    i32x4 qf[8];
    {
        const u8* qsrc = kq8 + (bbase + t7) * 8192 + lane * 16;
        #pragma unroll
        for (int s = 0; s < 8; s++) qf[s] = *(const i32x4*)(qsrc + (size_t)s * 1024);
    }
    float srq = srow[bb * 4096 + q0 + l31];

    i32x16 oacc[2] = {};
    i32x16 dsa = {};

    // prologue loads (mt = 0)
    i32x4 kf[8], vf[4][2], sf;
    float4 sg[4];
    {
        const u8* kb = kq8 + (bbase + w) * 8192 + lane * 16;
        #pragma unroll
        for (int s = 0; s < 8; s++) kf[s] = *(const i32x4*)(kb + (size_t)s * 1024);
        #pragma unroll
        for (int st = 0; st < 4; st++)
            #pragma unroll
            for (int e = 0; e < 2; e++)
                vf[st][e] = *(const i32x4*)(vp8 + ((size_t)((bbase + st) * 9 + 2 * w + e)) * 1024 + lane * 16);
        sf = *(const i32x4*)(vp8 + ((size_t)((bbase + w) * 9 + 8)) * 1024 + lane * 16);
        const float* srm = srow + bb * 4096 + w * 32;
        #pragma unroll
        for (int g = 0; g < 4; g++) sg[g] = *(const float4*)(srm + g * 8 + h * 4);
    }

    for (int mt = 0; mt < 32; mt++) {
        // S^T = K x Q^T, two independent chains (halve serial MFMA dep latency)
        i32x16 s0 = {}, s1 = {};
        __builtin_amdgcn_s_setprio(1);
        #pragma unroll
        for (int s = 0; s < 8; s += 2) {
            s0 = __builtin_amdgcn_mfma_i32_32x32x32_i8(kf[s], qf[s], s0, 0, 0, 0);
            s1 = __builtin_amdgcn_mfma_i32_32x32x32_i8(kf[s + 1], qf[s + 1], s1, 0, 0, 0);
        }
        __builtin_amdgcn_s_setprio(0);
        // prefetch next kf (kf dead after QK issue; ~400cy of compute before next use)
        if (mt + 1 < 32) {
            const u8* kb = kq8 + (bbase + (mt + 1) * 4 + w) * 8192 + lane * 16;
            #pragma unroll
            for (int s = 0; s < 8; s++) kf[s] = *(const i32x4*)(kb + (size_t)s * 1024);
        }

        // dequant -> softsign -> magic-round to i8 (rne), pack in sigma order
        float cf[16];
        #pragma unroll
        for (int r = 0; r < 16; r++) {
            float sm = ((const float*)&sg[r >> 2])[r & 3] * srq;
            float xs = (float)(s0[r] + s1[r]) * sm;
            float p = xs * __builtin_amdgcn_rcpf(1.0f + fabsf(xs));
            cf[r] = fmaf(p, 127.0f, MAGIC);
        }
        if (mt + 1 < 32) {
            const float* srm = srow + bb * 4096 + (mt + 1) * 128 + w * 32;
            #pragma unroll
            for (int g = 0; g < 4; g++) sg[g] = *(const float4*)(srm + g * 8 + h * 4);
        }
        union { u32 wd[4]; i32x4 v; } pu;
        pu.wd[0] = packlow4(cf[0], cf[1], cf[2], cf[3]);
        pu.wd[1] = packlow4(cf[4], cf[5], cf[6], cf[7]);
        pu.wd[2] = packlow4(cf[8], cf[9], cf[10], cf[11]);
        pu.wd[3] = packlow4(cf[12], cf[13], cf[14], cf[15]);
        i32x4 pf = pu.v;

        // ds partial for this wave's strip (uses own pf, no exchange needed)
        dsa = __builtin_amdgcn_mfma_i32_32x32x32_i8(pf, sf, dsa, 0, 0, 0);
        if (mt + 1 < 32)
            sf = *(const i32x4*)(vp8 + ((size_t)((bbase + (mt + 1) * 4 + w) * 9 + 8)) * 1024 + lane * 16);

        // share P frags across waves (write(i) -> barrier(i) -> read(i); dbuf makes
        // one barrier/iter safe: writing buf[(i+2)&1] requires passing barrier(i+1),
        // which implies all waves completed their read(i))
        pbuf[mt & 1][w][lane] = pf;
        __syncthreads();
        i32x4 pl[4];
        #pragma unroll
        for (int st = 0; st < 4; st++) pl[st] = pbuf[mt & 1][st][lane];

        // O(cols 2w,2w+1) += sum_st P(st) x Vt(st)
        __builtin_amdgcn_s_setprio(1);
        #pragma unroll
        for (int st = 0; st < 4; st++) {
            oacc[0] = __builtin_amdgcn_mfma_i32_32x32x32_i8(pl[st], vf[st][0], oacc[0], 0, 0, 0);
            oacc[1] = __builtin_amdgcn_mfma_i32_32x32x32_i8(pl[st], vf[st][1], oacc[1], 0, 0, 0);
        }
        __builtin_amdgcn_s_setprio(0);
        // prefetch next vf (full iteration of latency window)
        if (mt + 1 < 32) {
            #pragma unroll
            for (int st = 0; st < 4; st++)
                #pragma unroll
                for (int e = 0; e < 2; e++)
                    vf[st][e] = *(const i32x4*)(vp8 + ((size_t)((bbase + (mt + 1) * 4 + st) * 9 + 2 * w + e)) * 1024 + lane * 16);
        }
    }

    // ---- epilogue: no cross-wave O reduction needed; each wave owns its cols ----
    if (l31 == 0) {
        #pragma unroll
        for (int r = 0; r < 16; r++) dsqi[w][(r & 3) + 8 * (r >> 2) + 4 * h] = dsa[r];
    }
    #pragma unroll
    for (int e = 0; e < 2; e++) {
        #pragma unroll
        for (int r = 0; r < 16; r++) {
            int row = (r & 3) + 8 * (r >> 2) + 4 * h;
            dval_out[((size_t)(bb * 4096 + q0 + row)) * 256 + (2 * w + e) * 32 + l31] =
                (float)oacc[e][r] * DPV;
        }
    }
    __syncthreads();
    if (w == 0 && lane < 32) {
        int d = dsqi[0][lane] + dsqi[1][lane] + dsqi[2][lane] + dsqi[3][lane];
        ds_out[bb * 4096 + q0 + lane] = (float)d * DST;
    }
}

extern "C" void kernel_launch(void* const* d_in, const int* in_sizes, int n_in,
                              void* d_out, int out_size, void* d_ws, size_t ws_size,
                              hipStream_t stream) {
    const float* val   = (const float*)d_in[0];
    const float* state = (const float*)d_in[1];
    const float* Wv    = (const float*)d_in[2];

    float* ds_out   = (float*)d_out;
    float* dval_out = ds_out + NB * NN;

    u8*  kq8 = (u8*)d_ws;                                      // 4 MB
    u8*  vp8 = kq8 + (size_t)NB * NN * ND;                     // 4.5 MB
    u16* wv  = (u16*)(vp8 + (size_t)NB * 128 * 9216);          // 128 KB
    float* srow = (float*)(wv + 8 * 16 * 512);                 // 64 KB

    k_wv<<<8, 256, 0, stream>>>(Wv, wv);
    k_prep<<<516, 256, 0, stream>>>(val, state, wv, kq8, srow, vp8);
    k_main<<<512, 256, 0, stream>>>(kq8, vp8, srow, ds_out, dval_out);
}

// Round 13
// 134.487 us; speedup vs baseline: 1.2888x; 1.0142x over previous
//
#include <hip/hip_runtime.h>

typedef unsigned short u16;
typedef unsigned char u8;
typedef unsigned int u32;
typedef __bf16 bf16x8 __attribute__((ext_vector_type(8)));
typedef float  f32x16 __attribute__((ext_vector_type(16)));
typedef int    i32x4  __attribute__((ext_vector_type(4)));
typedef int    i32x16 __attribute__((ext_vector_type(16)));

#define NB 4
#define NN 4096
#define ND 256

#define QPV (127.0f / 4.5f)        // pv quant scale
#define DPV (4.5f / 16129.0f)      // O dequant
#define QST (127.0f / 4.6f)        // state quant scale
#define DST (4.6f / 16129.0f)      // ds dequant
#define MAGIC 12582912.0f          // 1.5*2^23: fma(x,s,MAGIC) -> low byte = int8(x*s) rne

__device__ __forceinline__ u16 f2bf(float x) { return __builtin_bit_cast(u16, (__bf16)x); }
__device__ __forceinline__ u32 fbits(float x) { return __builtin_bit_cast(u32, x); }

// pack low bytes of 4 magic-biased floats into one dword (3 x v_perm_b32)
__device__ __forceinline__ u32 packlow4(float a, float b, float c, float d) {
    u32 p = __builtin_amdgcn_perm(fbits(b), fbits(a), 0x00000400u);
    u32 q = __builtin_amdgcn_perm(fbits(d), fbits(c), 0x00000400u);
    return __builtin_amdgcn_perm(q, p, 0x05040100u);
}

// ---- sigma k-order convention (R9): position (h, byte 4g+j) holds logical
// m = 8g+j+4h on BOTH the pf (A) and vp8 (B) sides -> MFMA k-sum bit-identical,
// no cross-half shuffle, no LDS transpose in prep.

// ws layout:
//  kq8 : [b*128+strip][s8][lane64][16B]    i8 val frags, 4 MB
//  vp8 : [b*128+strip][slot9][lane64][16B] i8 frags (sigma): slot0..7 pv^T, slot8 state, 4.5 MB
//  wv  : [es8][s16][lane64][8]             bf16 Wv^T frags, 128 KB
//  srow: [b*4096+n] f32 = rowmax/127, 64 KB

// ---- Wv frag prep (runs first, 8 blocks) ----
__global__ __launch_bounds__(256) void k_wv(const float* __restrict__ Wv, u16* __restrict__ wv) {
    __shared__ u16 t2[256 * 33];
    int tid = threadIdx.x;
    int es = blockIdx.x, e0 = es * 32;
    #pragma unroll
    for (int k = 0; k < 8; k++) {
        int idx = tid + k * 256;
        int row = idx >> 3, c4 = idx & 7;
        float4 v = *(const float4*)(Wv + row * 256 + e0 + c4 * 4);
        u16* p = t2 + row * 33 + c4 * 4;
        p[0] = f2bf(v.x); p[1] = f2bf(v.y); p[2] = f2bf(v.z); p[3] = f2bf(v.w);
    }
    __syncthreads();
    u16* dst = wv + (size_t)es * 16 * 512;
    #pragma unroll
    for (int k = 0; k < 4; k++) {
        int flat = tid + k * 256;
        int s = flat >> 6, l = flat & 63;
        int l31 = l & 31, h = l >> 5;
        union { u16 o[8]; uint4 q; } u;
        #pragma unroll
        for (int j = 0; j < 8; j++) u.o[j] = t2[(s * 16 + h * 8 + j) * 33 + l31];
        *(uint4*)(dst + (size_t)flat * 8) = u.q;
    }
}

// ---- prep: stage strip, rowmax, kq8 frags, FUSED pv -> vp8 frags (sigma-order) ----
__global__ __launch_bounds__(256) void k_prep(const float* __restrict__ val,
                                              const float* __restrict__ state,
                                              const u16* __restrict__ wvf,
                                              u8* __restrict__ kq8,
                                              float* __restrict__ srow,
                                              u8* __restrict__ vp8) {
    int tid = threadIdx.x;
    int bid = blockIdx.x;
    if (bid < 512) {
        __shared__ float t[32 * 257];
        __shared__ float rmax[32];
        const float* src = val + (size_t)bid * 32 * 256;
        #pragma unroll
        for (int k = 0; k < 8; k++) {
            int idx = tid + k * 256;
            int row = idx >> 6, c4 = idx & 63;
            float4 v = *(const float4*)(src + row * 256 + c4 * 4);
            float* p = t + row * 257 + c4 * 4;
            p[0] = v.x; p[1] = v.y; p[2] = v.z; p[3] = v.w;
        }
        __syncthreads();
        {
            int row = tid >> 3, seg = tid & 7;
            float m = 0.0f;
            #pragma unroll
            for (int i = 0; i < 32; i++) m = fmaxf(m, fabsf(t[row * 257 + seg + i * 8]));
            m = fmaxf(m, __shfl_down(m, 4));
            m = fmaxf(m, __shfl_down(m, 2));
            m = fmaxf(m, __shfl_down(m, 1));
            if (seg == 0) {
                m = fmaxf(m, 1e-20f);
                rmax[row] = m;
                srow[bid * 32 + row] = m * (1.0f / 127.0f);
            }
        }
        __syncthreads();
        // i8 frags, per-row scale; |val|<=rmax so no clamp needed
        u8* dst8 = kq8 + (size_t)bid * 8192;
        #pragma unroll
        for (int k = 0; k < 2; k++) {
            int flat = tid + k * 256;
            int s = flat >> 6, l = flat & 63;
            int l31 = l & 31, h = l >> 5;
            float r127 = 127.0f / rmax[l31];
            const float* p = t + l31 * 257 + s * 32 + h * 16;
            u32 d[4];
            #pragma unroll
            for (int g = 0; g < 4; g++)
                d[g] = packlow4(fmaf(p[4 * g + 0], r127, MAGIC), fmaf(p[4 * g + 1], r127, MAGIC),
                                fmaf(p[4 * g + 2], r127, MAGIC), fmaf(p[4 * g + 3], r127, MAGIC));
            *(uint4*)(dst8 + (size_t)flat * 16) = make_uint4(d[0], d[1], d[2], d[3]);
        }
        // fused pv, sigma-order write (no LDS transpose)
        {
            int w = tid >> 6, lane = tid & 63;
            int l31 = lane & 31, h = lane >> 5;
            const u16* wv0 = wvf + ((size_t)((w * 2 + 0) * 16)) * 512 + lane * 8;
            const u16* wv1 = wvf + ((size_t)((w * 2 + 1) * 16)) * 512 + lane * 8;
            f32x16 acc0 = {}, acc1 = {};
            for (int s = 0; s < 16; s++) {
                union { u16 o[8]; bf16x8 v; } ua;
                const float* p = t + l31 * 257 + s * 16 + h * 8;
                #pragma unroll
                for (int j = 0; j < 8; j++) ua.o[j] = f2bf(p[j]);
                bf16x8 b0 = *(const bf16x8*)(wv0 + (size_t)s * 512);
                bf16x8 b1 = *(const bf16x8*)(wv1 + (size_t)s * 512);
                acc0 = __builtin_amdgcn_mfma_f32_32x32x16_bf16(ua.v, b0, acc0, 0, 0, 0);
                acc1 = __builtin_amdgcn_mfma_f32_32x32x16_bf16(ua.v, b1, acc1, 0, 0, 0);
            }
            union { u32 wd[4]; i32x4 v; } o0, o1;
            #pragma unroll
            for (int g = 0; g < 4; g++) {
                o0.wd[g] = packlow4(
                    fminf(fmaxf(acc0[4 * g + 0] * QPV, -127.0f), 127.0f) + MAGIC,
                    fminf(fmaxf(acc0[4 * g + 1] * QPV, -127.0f), 127.0f) + MAGIC,
                    fminf(fmaxf(acc0[4 * g + 2] * QPV, -127.0f), 127.0f) + MAGIC,
                    fminf(fmaxf(acc0[4 * g + 3] * QPV, -127.0f), 127.0f) + MAGIC);
                o1.wd[g] = packlow4(
                    fminf(fmaxf(acc1[4 * g + 0] * QPV, -127.0f), 127.0f) + MAGIC,
                    fminf(fmaxf(acc1[4 * g + 1] * QPV, -127.0f), 127.0f) + MAGIC,
                    fminf(fmaxf(acc1[4 * g + 2] * QPV, -127.0f), 127.0f) + MAGIC,
                    fminf(fmaxf(acc1[4 * g + 3] * QPV, -127.0f), 127.0f) + MAGIC);
            }
            *(i32x4*)(vp8 + ((size_t)(bid * 9 + w * 2 + 0)) * 1024 + lane * 16) = o0.v;
            *(i32x4*)(vp8 + ((size_t)(bid * 9 + w * 2 + 1)) * 1024 + lane * 16) = o1.v;
        }
    } else {
        int b = bid - 512;
        __shared__ u8 qs[4096];
        #pragma unroll
        for (int k = 0; k < 16; k++) {
            int i = tid + k * 256;
            float x = fminf(fmaxf(state[b * 4096 + i] * QST, -127.0f), 127.0f);
            qs[i] = (u8)(fbits(x + MAGIC) & 255);
        }
        __syncthreads();
        // slot 8 in sigma-order: dword g of lane (l31,h) = qs[strip*32 + 8g + 4h]
        #pragma unroll
        for (int k = 0; k < 32; k++) {
            int chunk = tid + k * 256;
            int strip = chunk >> 6, lane = chunk & 63, h = (lane >> 5) & 1;
            union { u32 wd[4]; i32x4 v; } u;
            #pragma unroll
            for (int g = 0; g < 4; g++)
                u.wd[g] = *(const u32*)(qs + strip * 32 + 8 * g + 4 * h);
            *(i32x4*)(vp8 + ((size_t)((b * 128 + strip) * 9 + 8)) * 1024 + (chunk & 63) * 16) = u.v;
        }
    }
}

// ---- main (R13 = R9 exact, best verified: k_main 65.2us, total 136.64us):
// et-split waves + LDS P-exchange, 1 barrier/iter; sigma-order pf (no shuffles);
// kf/vf/sf/sg single-buffer register prefetch for mt+1.
// Session-final notes: occupancy is doubly pinned at 2 waves/SIMD (grid 512x4
// AND ~190-total-reg footprint in the unified VGPR/AGPR file); every tested
// alternative (DMA staging R3, QK-ahead pipeline R6, non-draining barrier R7,
// m-split R10, register diet R11, setprio R12) was null or regressed.
__global__ __launch_bounds__(256, 2) void k_main(const u8* __restrict__ kq8,
                                                 const u8* __restrict__ vp8,
                                                 const float* __restrict__ srow,
                                                 float* __restrict__ ds_out,
                                                 float* __restrict__ dval_out) {
    __shared__ i32x4 pbuf[2][4][64];           // P frag exchange, double-buffered (8 KB)
    __shared__ int dsqi[4][32];

    int tid = threadIdx.x;
    int w = tid >> 6, lane = tid & 63;
    int l31 = lane & 31, h = lane >> 5;

    int id = blockIdx.x;                       // [0,512)
    int xcd = id & 7;
    int bb = xcd >> 1;
    int t7 = ((xcd & 1) << 6) | (id >> 3);     // q-strip [0,128)
    int q0 = t7 * 32;
    size_t bbase = (size_t)bb * 128;

    i32x4 qf[8];
    {
        const u8* qsrc = kq8 + (bbase + t7) * 8192 + lane * 16;
        #pragma unroll
        for (int s = 0; s < 8; s++) qf[s] = *(const i32x4*)(qsrc + (size_t)s * 1024);
    }
    float srq = srow[bb * 4096 + q0 + l31];

    i32x16 oacc[2] = {};
    i32x16 dsa = {};

    // prologue loads (mt = 0)
    i32x4 kf[8], vf[4][2], sf;
    float4 sg[4];
    {
        const u8* kb = kq8 + (bbase + w) * 8192 + lane * 16;
        #pragma unroll
        for (int s = 0; s < 8; s++) kf[s] = *(const i32x4*)(kb + (size_t)s * 1024);
        #pragma unroll
        for (int st = 0; st < 4; st++)
            #pragma unroll
            for (int e = 0; e < 2; e++)
                vf[st][e] = *(const i32x4*)(vp8 + ((size_t)((bbase + st) * 9 + 2 * w + e)) * 1024 + lane * 16);
        sf = *(const i32x4*)(vp8 + ((size_t)((bbase + w) * 9 + 8)) * 1024 + lane * 16);
        const float* srm = srow + bb * 4096 + w * 32;
        #pragma unroll
        for (int g = 0; g < 4; g++) sg[g] = *(const float4*)(srm + g * 8 + h * 4);
    }

    for (int mt = 0; mt < 32; mt++) {
        // S^T = K x Q^T, two independent chains (halve serial MFMA dep latency)
        i32x16 s0 = {}, s1 = {};
        #pragma unroll
        for (int s = 0; s < 8; s += 2) {
            s0 = __builtin_amdgcn_mfma_i32_32x32x32_i8(kf[s], qf[s], s0, 0, 0, 0);
            s1 = __builtin_amdgcn_mfma_i32_32x32x32_i8(kf[s + 1], qf[s + 1], s1, 0, 0, 0);
        }
        // prefetch next kf (kf dead after QK issue; ~400cy of compute before next use)
        if (mt + 1 < 32) {
            const u8* kb = kq8 + (bbase + (mt + 1) * 4 + w) * 8192 + lane * 16;
            #pragma unroll
            for (int s = 0; s < 8; s++) kf[s] = *(const i32x4*)(kb + (size_t)s * 1024);
        }

        // dequant -> softsign -> magic-round to i8 (rne), pack in sigma order
        float cf[16];
        #pragma unroll
        for (int r = 0; r < 16; r++) {
            float sm = ((const float*)&sg[r >> 2])[r & 3] * srq;
            float xs = (float)(s0[r] + s1[r]) * sm;
            float p = xs * __builtin_amdgcn_rcpf(1.0f + fabsf(xs));
            cf[r] = fmaf(p, 127.0f, MAGIC);
        }
        if (mt + 1 < 32) {
            const float* srm = srow + bb * 4096 + (mt + 1) * 128 + w * 32;
            #pragma unroll
            for (int g = 0; g < 4; g++) sg[g] = *(const float4*)(srm + g * 8 + h * 4);
        }
        union { u32 wd[4]; i32x4 v; } pu;
        pu.wd[0] = packlow4(cf[0], cf[1], cf[2], cf[3]);
        pu.wd[1] = packlow4(cf[4], cf[5], cf[6], cf[7]);
        pu.wd[2] = packlow4(cf[8], cf[9], cf[10], cf[11]);
        pu.wd[3] = packlow4(cf[12], cf[13], cf[14], cf[15]);
        i32x4 pf = pu.v;

        // ds partial for this wave's strip (uses own pf, no exchange needed)
        dsa = __builtin_amdgcn_mfma_i32_32x32x32_i8(pf, sf, dsa, 0, 0, 0);
        if (mt + 1 < 32)
            sf = *(const i32x4*)(vp8 + ((size_t)((bbase + (mt + 1) * 4 + w) * 9 + 8)) * 1024 + lane * 16);

        // share P frags across waves (write(i) -> barrier(i) -> read(i); dbuf makes
        // one barrier/iter safe: writing buf[(i+2)&1] requires passing barrier(i+1),
        // which implies all waves completed their read(i))
        pbuf[mt & 1][w][lane] = pf;
        __syncthreads();
        i32x4 pl[4];
        #pragma unroll
        for (int st = 0; st < 4; st++) pl[st] = pbuf[mt & 1][st][lane];

        // O(cols 2w,2w+1) += sum_st P(st) x Vt(st)
        #pragma unroll
        for (int st = 0; st < 4; st++) {
            oacc[0] = __builtin_amdgcn_mfma_i32_32x32x32_i8(pl[st], vf[st][0], oacc[0], 0, 0, 0);
            oacc[1] = __builtin_amdgcn_mfma_i32_32x32x32_i8(pl[st], vf[st][1], oacc[1], 0, 0, 0);
        }
        // prefetch next vf (full iteration of latency window)
        if (mt + 1 < 32) {
            #pragma unroll
            for (int st = 0; st < 4; st++)
                #pragma unroll
                for (int e = 0; e < 2; e++)
                    vf[st][e] = *(const i32x4*)(vp8 + ((size_t)((bbase + (mt + 1) * 4 + st) * 9 + 2 * w + e)) * 1024 + lane * 16);
        }
    }

    // ---- epilogue: no cross-wave O reduction needed; each wave owns its cols ----
    if (l31 == 0) {
        #pragma unroll
        for (int r = 0; r < 16; r++) dsqi[w][(r & 3) + 8 * (r >> 2) + 4 * h] = dsa[r];
    }
    #pragma unroll
    for (int e = 0; e < 2; e++) {
        #pragma unroll
        for (int r = 0; r < 16; r++) {
            int row = (r & 3) + 8 * (r >> 2) + 4 * h;
            dval_out[((size_t)(bb * 4096 + q0 + row)) * 256 + (2 * w + e) * 32 + l31] =
                (float)oacc[e][r] * DPV;
        }
    }
    __syncthreads();
    if (w == 0 && lane < 32) {
        int d = dsqi[0][lane] + dsqi[1][lane] + dsqi[2][lane] + dsqi[3][lane];
        ds_out[bb * 4096 + q0 + lane] = (float)d * DST;
    }
}

extern "C" void kernel_launch(void* const* d_in, const int* in_sizes, int n_in,
                              void* d_out, int out_size, void* d_ws, size_t ws_size,
                              hipStream_t stream) {
    const float* val   = (const float*)d_in[0];
    const float* state = (const float*)d_in[1];
    const float* Wv    = (const float*)d_in[2];

    float* ds_out   = (float*)d_out;
    float* dval_out = ds_out + NB * NN;

    u8*  kq8 = (u8*)d_ws;                                      // 4 MB
    u8*  vp8 = kq8 + (size_t)NB * NN * ND;                     // 4.5 MB
    u16* wv  = (u16*)(vp8 + (size_t)NB * 128 * 9216);          // 128 KB
    float* srow = (float*)(wv + 8 * 16 * 512);                 // 64 KB

    k_wv<<<8, 256, 0, stream>>>(Wv, wv);
    k_prep<<<516, 256, 0, stream>>>(val, state, wv, kq8, srow, vp8);
    k_main<<<512, 256, 0, stream>>>(kq8, vp8, srow, ds_out, dval_out);
}